// Round 1
// baseline (195.743 us; speedup 1.0000x reference)
//
#include <hip/hip_runtime.h>

// Problem constants
#define B_   8192
#define K_   784      // IN_DIM
#define RP   1024     // unique w1 rows = HIDDEN / CF
#define HID  4096
#define OD   10
#define TS2  10240    // OUT_DIM*HIDDEN/CF

// Tiling
#define BM 128
#define BN 128
#define BK 16

__global__ __launch_bounds__(256, 2) void fused_tilednn(
    const float* __restrict__ x,
    const int*   __restrict__ tile1,
    const float* __restrict__ alphas1,
    const int*   __restrict__ tile2,
    const float* __restrict__ alphas2,
    float*       __restrict__ out)
{
    __shared__ float Xs[BK][BM];
    __shared__ float Ss[BK][BN];
    __shared__ float Vl[OD][BN];

    const int t  = threadIdx.x;
    const int tx = t & 15;
    const int ty = t >> 4;
    const int bm = blockIdx.x * BM;   // batch tile base
    const int bn = blockIdx.y * BN;   // r' tile base

    // ---- Vl[o][rl] = sum_c alphas1[c] * w2[o, c*1024 + bn + rl]
    // w2[o,h] = alphas2[(o*4096+h)/10240] * (2*tile2[(o*4096+h)%10240]-1)
    for (int e = t; e < OD * BN; e += 256) {
        const int o  = e / BN;
        const int rl = e - o * BN;
        const int rr = bn + rl;
        float v = 0.f;
        #pragma unroll
        for (int c = 0; c < 4; ++c) {
            const int idx = o * HID + c * RP + rr;
            const int ch  = idx / TS2;
            const float w2v = alphas2[ch] * (float)(2 * tile2[idx - ch * TS2] - 1);
            v = fmaf(alphas1[c], w2v, v);
        }
        Vl[o][rl] = v;
    }

    float acc[8][8];
    #pragma unroll
    for (int i = 0; i < 8; ++i)
        #pragma unroll
        for (int j = 0; j < 8; ++j) acc[i][j] = 0.f;

    const int lr = t >> 1;          // 0..127 : row within tile
    const int lk = (t & 1) << 3;    // 0 or 8 : k offset

    const float* xrow = x     + (size_t)(bm + lr) * K_;
    const int*   srow = tile1 + (size_t)(bn + lr) * K_;

    for (int k0 = 0; k0 < K_; k0 += BK) {
        __syncthreads();
        const float4 xa = *(const float4*)(xrow + k0 + lk);
        const float4 xb = *(const float4*)(xrow + k0 + lk + 4);
        const int4   sa = *(const int4*)(srow + k0 + lk);
        const int4   sb = *(const int4*)(srow + k0 + lk + 4);
        Xs[lk + 0][lr] = xa.x;
        Xs[lk + 1][lr] = xa.y;
        Xs[lk + 2][lr] = xa.z;
        Xs[lk + 3][lr] = xa.w;
        Xs[lk + 4][lr] = xb.x;
        Xs[lk + 5][lr] = xb.y;
        Xs[lk + 6][lr] = xb.z;
        Xs[lk + 7][lr] = xb.w;
        Ss[lk + 0][lr] = (float)(2 * sa.x - 1);
        Ss[lk + 1][lr] = (float)(2 * sa.y - 1);
        Ss[lk + 2][lr] = (float)(2 * sa.z - 1);
        Ss[lk + 3][lr] = (float)(2 * sa.w - 1);
        Ss[lk + 4][lr] = (float)(2 * sb.x - 1);
        Ss[lk + 5][lr] = (float)(2 * sb.y - 1);
        Ss[lk + 6][lr] = (float)(2 * sb.z - 1);
        Ss[lk + 7][lr] = (float)(2 * sb.w - 1);
        __syncthreads();
        #pragma unroll
        for (int k = 0; k < BK; ++k) {
            float av[8], bv[8];
            #pragma unroll
            for (int i = 0; i < 8; ++i) av[i] = Xs[k][ty * 8 + i];
            #pragma unroll
            for (int j = 0; j < 8; ++j) bv[j] = Ss[k][tx * 8 + j];
            #pragma unroll
            for (int i = 0; i < 8; ++i)
                #pragma unroll
                for (int j = 0; j < 8; ++j)
                    acc[i][j] = fmaf(av[i], bv[j], acc[i][j]);
        }
    }

    // ---- epilogue: relu, multiply by Vl, reduce over tx group, atomicAdd
    #pragma unroll
    for (int i = 0; i < 8; ++i)
        #pragma unroll
        for (int j = 0; j < 8; ++j) acc[i][j] = fmaxf(acc[i][j], 0.f);

    #pragma unroll
    for (int o = 0; o < OD; ++o) {
        float vv[8];
        #pragma unroll
        for (int j = 0; j < 8; ++j) vv[j] = Vl[o][tx * 8 + j];
        float p[8];
        #pragma unroll
        for (int i = 0; i < 8; ++i) {
            float s = 0.f;
            #pragma unroll
            for (int j = 0; j < 8; ++j) s = fmaf(acc[i][j], vv[j], s);
            p[i] = s;
        }
        #pragma unroll
        for (int m = 8; m >= 1; m >>= 1)
            #pragma unroll
            for (int i = 0; i < 8; ++i) p[i] += __shfl_xor(p[i], m, 16);
        if (tx == 0) {
            #pragma unroll
            for (int i = 0; i < 8; ++i)
                atomicAdd(&out[(size_t)(bm + ty * 8 + i) * OD + o], p[i]);
        }
    }
}

extern "C" void kernel_launch(void* const* d_in, const int* in_sizes, int n_in,
                              void* d_out, int out_size, void* d_ws, size_t ws_size,
                              hipStream_t stream) {
    const float* x       = (const float*)d_in[0];
    const int*   tile1   = (const int*)  d_in[1];
    const float* alphas1 = (const float*)d_in[2];
    const int*   tile2   = (const int*)  d_in[3];
    const float* alphas2 = (const float*)d_in[4];
    float*       out     = (float*)d_out;

    // harness poisons d_out once and never re-poisons; we accumulate with
    // atomics, so zero it every call (graph-capturable async memset).
    hipMemsetAsync(out, 0, (size_t)out_size * sizeof(float), stream);

    dim3 grid(B_ / BM, RP / BN);   // 64 x 8 = 512 blocks
    fused_tilednn<<<grid, 256, 0, stream>>>(x, tile1, alphas1, tile2, alphas2, out);
}

// Round 2
// 49.566 us; speedup vs baseline: 3.9491x; 3.9491x over previous
//
#include <hip/hip_runtime.h>

// ---------------- problem constants ----------------
#define B_    8192
#define K_    784       // IN_DIM
#define KP    832       // K padded to 13*64
#define NKB   13        // K blocks of 64
#define RP    1024      // unique w1 rows = HIDDEN/CF
#define HID   4096
#define OD    10
#define TS2   10240     // OUT_DIM*HIDDEN/CF

typedef __attribute__((ext_vector_type(8))) short  bf16x8;
typedef __attribute__((ext_vector_type(4))) short  short4v;
typedef __attribute__((ext_vector_type(4))) float  f32x4;

__device__ __forceinline__ unsigned short f2bf(float f) {
    unsigned u = __builtin_bit_cast(unsigned, f);
    u += 0x7fffu + ((u >> 16) & 1u);          // RNE
    return (unsigned short)(u >> 16);
}
__device__ __forceinline__ float bf2f(unsigned short h) {
    unsigned u = ((unsigned)h) << 16;
    return __builtin_bit_cast(float, u);
}

// ================= conversion: x -> bf16, padded+swizzled =================
// Xsw[row][kb][s][e] = x[row][kb*64 + (s^(row&7))*8 + e]  (0 beyond 784)
__global__ __launch_bounds__(256) void conv_x(const float* __restrict__ x,
                                              unsigned short* __restrict__ Xsw) {
    const int id = blockIdx.x * 256 + threadIdx.x;          // 8192*104 threads
    const int row = id / 104;
    const int rem = id - row * 104;
    const int kb = rem >> 3;
    const int s  = rem & 7;
    const int c  = s ^ (row & 7);
    const int kk = kb * 64 + c * 8;
    bf16x8 v;
    if (kk < K_) {
        const float* xp = x + (size_t)row * K_ + kk;
        f32x4 a = *(const f32x4*)xp;
        f32x4 b = *(const f32x4*)(xp + 4);
        v[0] = (short)f2bf(a.x); v[1] = (short)f2bf(a.y);
        v[2] = (short)f2bf(a.z); v[3] = (short)f2bf(a.w);
        v[4] = (short)f2bf(b.x); v[5] = (short)f2bf(b.y);
        v[6] = (short)f2bf(b.z); v[7] = (short)f2bf(b.w);
    } else {
        v = (bf16x8)0;
    }
    *(bf16x8*)(Xsw + (size_t)row * KP + kb * 64 + s * 8) = v;
}

// ================= conversion: tile1 -> +/-1 bf16, padded+swizzled =========
__global__ __launch_bounds__(256) void conv_s(const int* __restrict__ t1,
                                              unsigned short* __restrict__ Ssw) {
    const int id = blockIdx.x * 256 + threadIdx.x;          // 1024*104 threads
    const int row = id / 104;
    const int rem = id - row * 104;
    const int kb = rem >> 3;
    const int s  = rem & 7;
    const int c  = s ^ (row & 7);
    const int kk = kb * 64 + c * 8;
    bf16x8 v;
    if (kk < K_) {
        const int* tp = t1 + (size_t)row * K_ + kk;
        #pragma unroll
        for (int e = 0; e < 8; ++e)
            v[e] = (short)(tp[e] ? 0x3F80 : 0xBF80);        // +1.0 / -1.0 bf16
    } else {
        v = (bf16x8)0;
    }
    *(bf16x8*)(Ssw + (size_t)row * KP + kb * 64 + s * 8) = v;
}

// ================= V[o][r] = sum_c alphas1[c] * w2[o, c*1024+r]  (f32) =====
__global__ __launch_bounds__(256) void conv_v(const int* __restrict__ t2,
                                              const float* __restrict__ a1,
                                              const float* __restrict__ a2,
                                              float* __restrict__ V) {
    const int id = blockIdx.x * 256 + threadIdx.x;          // 10240 threads
    if (id >= OD * RP) return;
    const int o = id >> 10;
    const int r = id & 1023;
    float v = 0.f;
    #pragma unroll
    for (int c = 0; c < 4; ++c) {
        const int idx = o * HID + c * RP + r;
        const int ch  = idx / TS2;
        const float w2v = a2[ch] * (float)(2 * t2[idx - ch * TS2] - 1);
        v = fmaf(a1[c], w2v, v);
    }
    V[id] = v;
}

// ================= GEMM1: Hr = relu(X @ S^T) in bf16 ======================
// grid (64, 8); block 256 = 4 waves (2x2), wave tile 64x64, frags 4x4 of 16x16
__global__ __launch_bounds__(256) void gemm1(const unsigned short* __restrict__ Xsw,
                                             const unsigned short* __restrict__ Ssw,
                                             unsigned short* __restrict__ Hr) {
    __shared__ unsigned short Xs[128 * 64];   // [row][64], 128B rows, swizzled slots
    __shared__ unsigned short Ss[128 * 64];

    const int tid  = threadIdx.x;
    const int lane = tid & 63;
    const int wid  = tid >> 6;
    const int bm   = blockIdx.x * 128;
    const int bn   = blockIdx.y * 128;
    const int wr   = (wid >> 1) * 64;
    const int wc   = (wid & 1) * 64;

    f32x4 acc[4][4] = {};

    const int srow   = (lane >> 3);            // rows per 1KB chunk: 8
    const int sinrow = (lane & 7) << 3;        // ushort offset within 128B row

    for (int kb = 0; kb < NKB; ++kb) {
        __syncthreads();                       // prev compute done
        #pragma unroll
        for (int i = 0; i < 4; ++i) {
            const int off  = wid * 4096 + i * 1024;          // byte offset in 16KB tile
            const int row  = (off >> 7) + srow;              // 0..127
            const unsigned short* ga = Xsw + (size_t)(bm + row) * KP + kb * 64 + sinrow;
            const unsigned short* gb = Ssw + (size_t)(bn + row) * KP + kb * 64 + sinrow;
            __builtin_amdgcn_global_load_lds(
                (const __attribute__((address_space(1))) void*)ga,
                (__attribute__((address_space(3))) void*)(Xs + ((off >> 1) + lane * 8)),
                16, 0, 0);
            __builtin_amdgcn_global_load_lds(
                (const __attribute__((address_space(1))) void*)gb,
                (__attribute__((address_space(3))) void*)(Ss + ((off >> 1) + lane * 8)),
                16, 0, 0);
        }
        asm volatile("s_waitcnt vmcnt(0)" ::: "memory");
        __syncthreads();                       // tile ready

        #pragma unroll
        for (int ks = 0; ks < 2; ++ks) {
            bf16x8 af[4], bfr[4];
            const int t = ks * 4 + (lane >> 4);
            #pragma unroll
            for (int mi = 0; mi < 4; ++mi) {
                const int row = wr + mi * 16 + (lane & 15);
                af[mi] = *(const bf16x8*)&Xs[row * 64 + ((t ^ (row & 7)) << 3)];
            }
            #pragma unroll
            for (int ni = 0; ni < 4; ++ni) {
                const int row = wc + ni * 16 + (lane & 15);
                bfr[ni] = *(const bf16x8*)&Ss[row * 64 + ((t ^ (row & 7)) << 3)];
            }
            #pragma unroll
            for (int mi = 0; mi < 4; ++mi)
                #pragma unroll
                for (int ni = 0; ni < 4; ++ni)
                    acc[mi][ni] = __builtin_amdgcn_mfma_f32_16x16x32_bf16(
                        af[mi], bfr[ni], acc[mi][ni], 0, 0, 0);
        }
    }

    // epilogue: relu -> bf16 -> Hr[8192][1024]
    #pragma unroll
    for (int mi = 0; mi < 4; ++mi) {
        #pragma unroll
        for (int ni = 0; ni < 4; ++ni) {
            const int col = bn + wc + ni * 16 + (lane & 15);
            #pragma unroll
            for (int r = 0; r < 4; ++r) {
                const int rowg = bm + wr + mi * 16 + (lane >> 4) * 4 + r;
                Hr[(size_t)rowg * RP + col] = f2bf(fmaxf(acc[mi][ni][r], 0.f));
            }
        }
    }
}

// ================= GEMM2: out = Hr @ V^T  (wave per row) ==================
__global__ __launch_bounds__(256) void gemm2(const unsigned short* __restrict__ Hr,
                                             const float* __restrict__ V,
                                             float* __restrict__ out) {
    __shared__ float Vl[OD * RP];              // 40 KB
    const int tid = threadIdx.x;
    for (int i = tid; i < OD * RP / 4; i += 256)
        ((f32x4*)Vl)[i] = ((const f32x4*)V)[i];
    __syncthreads();

    const int lane = tid & 63;
    const int wid  = tid >> 6;
    const int b    = blockIdx.x * 4 + wid;

    float acc[OD];
    #pragma unroll
    for (int o = 0; o < OD; ++o) acc[o] = 0.f;

    #pragma unroll
    for (int q = 0; q < 4; ++q) {
        const int r = q * 256 + lane * 4;
        short4v hv = *(const short4v*)&Hr[(size_t)b * RP + r];
        float h0 = bf2f((unsigned short)hv[0]);
        float h1 = bf2f((unsigned short)hv[1]);
        float h2 = bf2f((unsigned short)hv[2]);
        float h3 = bf2f((unsigned short)hv[3]);
        #pragma unroll
        for (int o = 0; o < OD; ++o) {
            f32x4 v = *(const f32x4*)&Vl[o * RP + r];
            acc[o] += h0 * v.x + h1 * v.y + h2 * v.z + h3 * v.w;
        }
    }
    #pragma unroll
    for (int m = 1; m < 64; m <<= 1)
        #pragma unroll
        for (int o = 0; o < OD; ++o) acc[o] += __shfl_xor(acc[o], m);
    if (lane == 0) {
        #pragma unroll
        for (int o = 0; o < OD; ++o) out[(size_t)b * OD + o] = acc[o];
    }
}

// ================= fallback (round-1 f32 SIMT fused kernel) ================
#define BM 128
#define BN 128
#define BK 16
__global__ __launch_bounds__(256, 2) void fused_tilednn(
    const float* __restrict__ x, const int* __restrict__ tile1,
    const float* __restrict__ alphas1, const int* __restrict__ tile2,
    const float* __restrict__ alphas2, float* __restrict__ out)
{
    __shared__ float XsF[BK][BM];
    __shared__ float SsF[BK][BN];
    __shared__ float Vl[OD][BN];
    const int t = threadIdx.x, tx = t & 15, ty = t >> 4;
    const int bm = blockIdx.x * BM, bn = blockIdx.y * BN;
    for (int e = t; e < OD * BN; e += 256) {
        const int o = e / BN, rl = e - o * BN, rr = bn + rl;
        float v = 0.f;
        #pragma unroll
        for (int c = 0; c < 4; ++c) {
            const int idx = o * HID + c * RP + rr;
            const int ch = idx / TS2;
            v = fmaf(alphas1[c], alphas2[ch] * (float)(2 * tile2[idx - ch * TS2] - 1), v);
        }
        Vl[o][rl] = v;
    }
    float acc[8][8];
    #pragma unroll
    for (int i = 0; i < 8; ++i)
        #pragma unroll
        for (int j = 0; j < 8; ++j) acc[i][j] = 0.f;
    const int lr = t >> 1, lk = (t & 1) << 3;
    const float* xrow = x + (size_t)(bm + lr) * K_;
    const int* srow = tile1 + (size_t)(bn + lr) * K_;
    for (int k0 = 0; k0 < K_; k0 += BK) {
        __syncthreads();
        const float4 xa = *(const float4*)(xrow + k0 + lk);
        const float4 xb = *(const float4*)(xrow + k0 + lk + 4);
        const int4 sa = *(const int4*)(srow + k0 + lk);
        const int4 sb = *(const int4*)(srow + k0 + lk + 4);
        XsF[lk+0][lr]=xa.x; XsF[lk+1][lr]=xa.y; XsF[lk+2][lr]=xa.z; XsF[lk+3][lr]=xa.w;
        XsF[lk+4][lr]=xb.x; XsF[lk+5][lr]=xb.y; XsF[lk+6][lr]=xb.z; XsF[lk+7][lr]=xb.w;
        SsF[lk+0][lr]=(float)(2*sa.x-1); SsF[lk+1][lr]=(float)(2*sa.y-1);
        SsF[lk+2][lr]=(float)(2*sa.z-1); SsF[lk+3][lr]=(float)(2*sa.w-1);
        SsF[lk+4][lr]=(float)(2*sb.x-1); SsF[lk+5][lr]=(float)(2*sb.y-1);
        SsF[lk+6][lr]=(float)(2*sb.z-1); SsF[lk+7][lr]=(float)(2*sb.w-1);
        __syncthreads();
        #pragma unroll
        for (int k = 0; k < BK; ++k) {
            float av[8], bv[8];
            #pragma unroll
            for (int i = 0; i < 8; ++i) av[i] = XsF[k][ty*8+i];
            #pragma unroll
            for (int j = 0; j < 8; ++j) bv[j] = SsF[k][tx*8+j];
            #pragma unroll
            for (int i = 0; i < 8; ++i)
                #pragma unroll
                for (int j = 0; j < 8; ++j) acc[i][j] = fmaf(av[i], bv[j], acc[i][j]);
        }
    }
    #pragma unroll
    for (int i = 0; i < 8; ++i)
        #pragma unroll
        for (int j = 0; j < 8; ++j) acc[i][j] = fmaxf(acc[i][j], 0.f);
    #pragma unroll
    for (int o = 0; o < OD; ++o) {
        float vv[8];
        #pragma unroll
        for (int j = 0; j < 8; ++j) vv[j] = Vl[o][tx*8+j];
        float p[8];
        #pragma unroll
        for (int i = 0; i < 8; ++i) {
            float s = 0.f;
            #pragma unroll
            for (int j = 0; j < 8; ++j) s = fmaf(acc[i][j], vv[j], s);
            p[i] = s;
        }
        #pragma unroll
        for (int m = 8; m >= 1; m >>= 1)
            #pragma unroll
            for (int i = 0; i < 8; ++i) p[i] += __shfl_xor(p[i], m, 16);
        if (tx == 0) {
            #pragma unroll
            for (int i = 0; i < 8; ++i)
                atomicAdd(&out[(size_t)(bm + ty*8 + i) * OD + o], p[i]);
        }
    }
}

// ================= launch ==================================================
extern "C" void kernel_launch(void* const* d_in, const int* in_sizes, int n_in,
                              void* d_out, int out_size, void* d_ws, size_t ws_size,
                              hipStream_t stream) {
    const float* x       = (const float*)d_in[0];
    const int*   tile1   = (const int*)  d_in[1];
    const float* alphas1 = (const float*)d_in[2];
    const int*   tile2   = (const int*)  d_in[3];
    const float* alphas2 = (const float*)d_in[4];
    float*       out     = (float*)d_out;

    const size_t OFF_X = 0;                                   // 8192*832*2 = 13,631,488
    const size_t OFF_S = OFF_X + (size_t)B_ * KP * 2;         // + 1024*832*2 = 1,703,936
    const size_t OFF_V = OFF_S + (size_t)RP * KP * 2;         // + 10*1024*4  = 40,960
    const size_t OFF_H = OFF_V + (size_t)OD * RP * 4;         // + 8192*1024*2 = 16,777,216
    const size_t NEED  = OFF_H + (size_t)B_ * RP * 2;         // ~30.7 MB

    if (ws_size < NEED) {
        hipMemsetAsync(out, 0, (size_t)out_size * sizeof(float), stream);
        dim3 grid(B_ / BM, RP / BN);
        fused_tilednn<<<grid, 256, 0, stream>>>(x, tile1, alphas1, tile2, alphas2, out);
        return;
    }

    unsigned short* Xsw = (unsigned short*)((char*)d_ws + OFF_X);
    unsigned short* Ssw = (unsigned short*)((char*)d_ws + OFF_S);
    float*          V   = (float*)((char*)d_ws + OFF_V);
    unsigned short* Hr  = (unsigned short*)((char*)d_ws + OFF_H);

    conv_x<<<(B_ * 104) / 256, 256, 0, stream>>>(x, Xsw);
    conv_s<<<(RP * 104) / 256, 256, 0, stream>>>(tile1, Ssw);
    conv_v<<<(OD * RP + 255) / 256, 256, 0, stream>>>(tile2, alphas1, alphas2, V);
    dim3 g1(B_ / 128, RP / 128);
    gemm1<<<g1, 256, 0, stream>>>(Xsw, Ssw, Hr);
    gemm2<<<B_ / 4, 256, 0, stream>>>(Hr, V, out);
}

// Round 3
// 43.891 us; speedup vs baseline: 4.4598x; 1.1293x over previous
//
#include <hip/hip_runtime.h>

// ---------------- problem constants ----------------
#define B_    8192
#define K_    784       // IN_DIM
#define KP    832       // K padded to 13*64
#define NKB   13        // K blocks of 64
#define RP    1024      // unique w1 rows = HIDDEN/CF
#define HID   4096
#define OD    10
#define TS2   10240     // OUT_DIM*HIDDEN/CF

#define NB_X  3328      // 8192*104/256
#define NB_S  416       // 1024*104/256
#define NB_V  40        // 10240/256

typedef __attribute__((ext_vector_type(8))) short  bf16x8;
typedef __attribute__((ext_vector_type(4))) short  short4v;
typedef __attribute__((ext_vector_type(4))) float  f32x4;

__device__ __forceinline__ unsigned short f2bf(float f) {
    unsigned u = __builtin_bit_cast(unsigned, f);
    u += 0x7fffu + ((u >> 16) & 1u);          // RNE
    return (unsigned short)(u >> 16);
}
__device__ __forceinline__ float bf2f(unsigned short h) {
    unsigned u = ((unsigned)h) << 16;
    return __builtin_bit_cast(float, u);
}

// ================= merged prep kernel =====================================
// blocks [0, NB_X)            : x -> bf16, padded + per-row swizzled
// blocks [NB_X, NB_X+NB_S)    : tile1 -> +/-1 bf16, padded + swizzled
// blocks [NB_X+NB_S, ...+NB_V): V[o][r] = sum_c a1[c] * w2[o, c*1024+r]
__global__ __launch_bounds__(256) void prep(
    const float* __restrict__ x, const int* __restrict__ t1,
    const int* __restrict__ t2, const float* __restrict__ a1,
    const float* __restrict__ a2,
    unsigned short* __restrict__ Xsw, unsigned short* __restrict__ Ssw,
    float* __restrict__ V)
{
    const int b = blockIdx.x;
    if (b < NB_X) {
        const int id = b * 256 + threadIdx.x;
        const int row = id / 104;
        const int rem = id - row * 104;
        const int kb = rem >> 3;
        const int s  = rem & 7;
        const int kk = kb * 64 + (s ^ (row & 7)) * 8;
        bf16x8 v;
        if (kk < K_) {
            const float* xp = x + (size_t)row * K_ + kk;
            f32x4 a = *(const f32x4*)xp;
            f32x4 c = *(const f32x4*)(xp + 4);
            v[0] = (short)f2bf(a.x); v[1] = (short)f2bf(a.y);
            v[2] = (short)f2bf(a.z); v[3] = (short)f2bf(a.w);
            v[4] = (short)f2bf(c.x); v[5] = (short)f2bf(c.y);
            v[6] = (short)f2bf(c.z); v[7] = (short)f2bf(c.w);
        } else {
            v = (bf16x8)0;
        }
        *(bf16x8*)(Xsw + (size_t)row * KP + kb * 64 + s * 8) = v;
    } else if (b < NB_X + NB_S) {
        const int id = (b - NB_X) * 256 + threadIdx.x;
        const int row = id / 104;
        const int rem = id - row * 104;
        const int kb = rem >> 3;
        const int s  = rem & 7;
        const int kk = kb * 64 + (s ^ (row & 7)) * 8;
        bf16x8 v;
        if (kk < K_) {
            const int* tp = t1 + (size_t)row * K_ + kk;
            #pragma unroll
            for (int e = 0; e < 8; ++e)
                v[e] = (short)(tp[e] ? 0x3F80 : 0xBF80);
        } else {
            v = (bf16x8)0;
        }
        *(bf16x8*)(Ssw + (size_t)row * KP + kb * 64 + s * 8) = v;
    } else {
        const int id = (b - NB_X - NB_S) * 256 + threadIdx.x;   // < 10240
        const int o = id >> 10;
        const int r = id & 1023;
        float v = 0.f;
        #pragma unroll
        for (int c = 0; c < 4; ++c) {
            const int idx = o * HID + c * RP + r;
            const int ch  = idx / TS2;
            const float w2v = a2[ch] * (float)(2 * t2[idx - ch * TS2] - 1);
            v = fmaf(a1[c], w2v, v);
        }
        V[id] = v;
    }
}

// ================= GEMM1: Hr = relu(X @ S^T) in bf16, pipelined ===========
// grid 512 (XCD-chunked swizzle); block 256 = 4 waves (2x2), wave tile 64x64
__global__ __launch_bounds__(256) void gemm1(const unsigned short* __restrict__ Xsw,
                                             const unsigned short* __restrict__ Ssw,
                                             unsigned short* __restrict__ Hr) {
    __shared__ unsigned short Xs[2][128 * 64];   // double-buffered, 64 KB total
    __shared__ unsigned short Ss[2][128 * 64];

    const int tid  = threadIdx.x;
    const int lane = tid & 63;
    const int wid  = tid >> 6;

    // bijective XCD-chunked swizzle: XCD k owns bm-tiles [8k, 8k+8) x all bn
    const int swz = (blockIdx.x & 7) * 64 + (blockIdx.x >> 3);
    const int bm  = (swz >> 3) * 128;
    const int bn  = (swz & 7) * 128;

    const int wr = (wid >> 1) * 64;
    const int wc = (wid & 1) * 64;

    const int srow   = lane >> 3;              // 0..7 rows per 1KB chunk
    const int sinrow = (lane & 7) << 3;        // ushort offset within 128B row

    f32x4 acc[4][4] = {};

    // stage K-block KB into buffer BUF (8 global_load_lds per wave)
#define STAGE(KB, BUF)                                                          \
    do {                                                                        \
        _Pragma("unroll")                                                       \
        for (int i = 0; i < 4; ++i) {                                           \
            const int offB = wid * 4096 + i * 1024;   /* bytes in 16KB tile */  \
            const int row  = (offB >> 7) + srow;                                \
            const unsigned short* ga =                                          \
                Xsw + (size_t)(bm + row) * KP + (KB) * 64 + sinrow;             \
            const unsigned short* gb =                                          \
                Ssw + (size_t)(bn + row) * KP + (KB) * 64 + sinrow;             \
            __builtin_amdgcn_global_load_lds(                                   \
                (const __attribute__((address_space(1))) void*)ga,              \
                (__attribute__((address_space(3))) void*)(&Xs[BUF][offB >> 1]), \
                16, 0, 0);                                                      \
            __builtin_amdgcn_global_load_lds(                                   \
                (const __attribute__((address_space(1))) void*)gb,              \
                (__attribute__((address_space(3))) void*)(&Ss[BUF][offB >> 1]), \
                16, 0, 0);                                                      \
        }                                                                       \
    } while (0)

    STAGE(0, 0);                               // prologue: 8 loads in flight

    for (int kb = 0; kb < NKB; ++kb) {
        const int cur = kb & 1;
        if (kb + 1 < NKB) {
            STAGE(kb + 1, cur ^ 1);            // next tile: +8 loads
            // wait until only the 8 just-issued remain -> current tile landed
            asm volatile("s_waitcnt vmcnt(8)" ::: "memory");
        } else {
            asm volatile("s_waitcnt vmcnt(0)" ::: "memory");
        }
        __builtin_amdgcn_s_barrier();          // raw: does NOT drain vmcnt
        __builtin_amdgcn_sched_barrier(0);     // pin: no hoist above barrier

        #pragma unroll
        for (int ks = 0; ks < 2; ++ks) {
            bf16x8 af[4], bfr[4];
            const int t = ks * 4 + (lane >> 4);
            #pragma unroll
            for (int mi = 0; mi < 4; ++mi) {
                const int row = wr + mi * 16 + (lane & 15);
                af[mi] = *(const bf16x8*)&Xs[cur][row * 64 + ((t ^ (row & 7)) << 3)];
            }
            #pragma unroll
            for (int ni = 0; ni < 4; ++ni) {
                const int row = wc + ni * 16 + (lane & 15);
                bfr[ni] = *(const bf16x8*)&Ss[cur][row * 64 + ((t ^ (row & 7)) << 3)];
            }
            #pragma unroll
            for (int mi = 0; mi < 4; ++mi)
                #pragma unroll
                for (int ni = 0; ni < 4; ++ni)
                    acc[mi][ni] = __builtin_amdgcn_mfma_f32_16x16x32_bf16(
                        af[mi], bfr[ni], acc[mi][ni], 0, 0, 0);
        }

        __builtin_amdgcn_sched_barrier(0);     // pin: no sink below barrier
        __builtin_amdgcn_s_barrier();          // all done reading cur buffer
    }
#undef STAGE

    // epilogue: relu -> bf16 -> Hr[8192][1024]
    #pragma unroll
    for (int mi = 0; mi < 4; ++mi) {
        #pragma unroll
        for (int ni = 0; ni < 4; ++ni) {
            const int col = bn + wc + ni * 16 + (lane & 15);
            #pragma unroll
            for (int r = 0; r < 4; ++r) {
                const int rowg = bm + wr + mi * 16 + (lane >> 4) * 4 + r;
                Hr[(size_t)rowg * RP + col] = f2bf(fmaxf(acc[mi][ni][r], 0.f));
            }
        }
    }
}

// ================= GEMM2: out = Hr @ V^T  (wave per row) ==================
__global__ __launch_bounds__(256) void gemm2(const unsigned short* __restrict__ Hr,
                                             const float* __restrict__ V,
                                             float* __restrict__ out) {
    __shared__ float Vl[OD * RP];              // 40 KB
    const int tid = threadIdx.x;
    for (int i = tid; i < OD * RP / 4; i += 256)
        ((f32x4*)Vl)[i] = ((const f32x4*)V)[i];
    __syncthreads();

    const int lane = tid & 63;
    const int wid  = tid >> 6;
    const int b    = blockIdx.x * 4 + wid;

    float acc[OD];
    #pragma unroll
    for (int o = 0; o < OD; ++o) acc[o] = 0.f;

    #pragma unroll
    for (int q = 0; q < 4; ++q) {
        const int r = q * 256 + lane * 4;
        short4v hv = *(const short4v*)&Hr[(size_t)b * RP + r];
        float h0 = bf2f((unsigned short)hv[0]);
        float h1 = bf2f((unsigned short)hv[1]);
        float h2 = bf2f((unsigned short)hv[2]);
        float h3 = bf2f((unsigned short)hv[3]);
        #pragma unroll
        for (int o = 0; o < OD; ++o) {
            f32x4 v = *(const f32x4*)&Vl[o * RP + r];
            acc[o] += h0 * v.x + h1 * v.y + h2 * v.z + h3 * v.w;
        }
    }
    #pragma unroll
    for (int m = 1; m < 64; m <<= 1)
        #pragma unroll
        for (int o = 0; o < OD; ++o) acc[o] += __shfl_xor(acc[o], m);
    if (lane == 0) {
        #pragma unroll
        for (int o = 0; o < OD; ++o) out[(size_t)b * OD + o] = acc[o];
    }
}

// ================= fallback (round-1 f32 SIMT fused kernel) ================
#define BM 128
#define BN 128
#define BK 16
__global__ __launch_bounds__(256, 2) void fused_tilednn(
    const float* __restrict__ x, const int* __restrict__ tile1,
    const float* __restrict__ alphas1, const int* __restrict__ tile2,
    const float* __restrict__ alphas2, float* __restrict__ out)
{
    __shared__ float XsF[BK][BM];
    __shared__ float SsF[BK][BN];
    __shared__ float Vl[OD][BN];
    const int t = threadIdx.x, tx = t & 15, ty = t >> 4;
    const int bm = blockIdx.x * BM, bn = blockIdx.y * BN;
    for (int e = t; e < OD * BN; e += 256) {
        const int o = e / BN, rl = e - o * BN, rr = bn + rl;
        float v = 0.f;
        #pragma unroll
        for (int c = 0; c < 4; ++c) {
            const int idx = o * HID + c * RP + rr;
            const int ch = idx / TS2;
            v = fmaf(alphas1[c], alphas2[ch] * (float)(2 * tile2[idx - ch * TS2] - 1), v);
        }
        Vl[o][rl] = v;
    }
    float acc[8][8];
    #pragma unroll
    for (int i = 0; i < 8; ++i)
        #pragma unroll
        for (int j = 0; j < 8; ++j) acc[i][j] = 0.f;
    const int lr = t >> 1, lk = (t & 1) << 3;
    const float* xrow = x + (size_t)(bm + lr) * K_;
    const int* srow = tile1 + (size_t)(bn + lr) * K_;
    for (int k0 = 0; k0 < K_; k0 += BK) {
        __syncthreads();
        const float4 xa = *(const float4*)(xrow + k0 + lk);
        const float4 xb = *(const float4*)(xrow + k0 + lk + 4);
        const int4 sa = *(const int4*)(srow + k0 + lk);
        const int4 sb = *(const int4*)(srow + k0 + lk + 4);
        XsF[lk+0][lr]=xa.x; XsF[lk+1][lr]=xa.y; XsF[lk+2][lr]=xa.z; XsF[lk+3][lr]=xa.w;
        XsF[lk+4][lr]=xb.x; XsF[lk+5][lr]=xb.y; XsF[lk+6][lr]=xb.z; XsF[lk+7][lr]=xb.w;
        SsF[lk+0][lr]=(float)(2*sa.x-1); SsF[lk+1][lr]=(float)(2*sa.y-1);
        SsF[lk+2][lr]=(float)(2*sa.z-1); SsF[lk+3][lr]=(float)(2*sa.w-1);
        SsF[lk+4][lr]=(float)(2*sb.x-1); SsF[lk+5][lr]=(float)(2*sb.y-1);
        SsF[lk+6][lr]=(float)(2*sb.z-1); SsF[lk+7][lr]=(float)(2*sb.w-1);
        __syncthreads();
        #pragma unroll
        for (int k = 0; k < BK; ++k) {
            float av[8], bv[8];
            #pragma unroll
            for (int i = 0; i < 8; ++i) av[i] = XsF[k][ty*8+i];
            #pragma unroll
            for (int j = 0; j < 8; ++j) bv[j] = SsF[k][tx*8+j];
            #pragma unroll
            for (int i = 0; i < 8; ++i)
                #pragma unroll
                for (int j = 0; j < 8; ++j) acc[i][j] = fmaf(av[i], bv[j], acc[i][j]);
        }
    }
    #pragma unroll
    for (int i = 0; i < 8; ++i)
        #pragma unroll
        for (int j = 0; j < 8; ++j) acc[i][j] = fmaxf(acc[i][j], 0.f);
    #pragma unroll
    for (int o = 0; o < OD; ++o) {
        float vv[8];
        #pragma unroll
        for (int j = 0; j < 8; ++j) vv[j] = Vl[o][tx*8+j];
        float p[8];
        #pragma unroll
        for (int i = 0; i < 8; ++i) {
            float s = 0.f;
            #pragma unroll
            for (int j = 0; j < 8; ++j) s = fmaf(acc[i][j], vv[j], s);
            p[i] = s;
        }
        #pragma unroll
        for (int m = 8; m >= 1; m >>= 1)
            #pragma unroll
            for (int i = 0; i < 8; ++i) p[i] += __shfl_xor(p[i], m, 16);
        if (tx == 0) {
            #pragma unroll
            for (int i = 0; i < 8; ++i)
                atomicAdd(&out[(size_t)(bm + ty*8 + i) * OD + o], p[i]);
        }
    }
}

// ================= launch ==================================================
extern "C" void kernel_launch(void* const* d_in, const int* in_sizes, int n_in,
                              void* d_out, int out_size, void* d_ws, size_t ws_size,
                              hipStream_t stream) {
    const float* x       = (const float*)d_in[0];
    const int*   tile1   = (const int*)  d_in[1];
    const float* alphas1 = (const float*)d_in[2];
    const int*   tile2   = (const int*)  d_in[3];
    const float* alphas2 = (const float*)d_in[4];
    float*       out     = (float*)d_out;

    const size_t OFF_X = 0;                                   // 8192*832*2
    const size_t OFF_S = OFF_X + (size_t)B_ * KP * 2;
    const size_t OFF_V = OFF_S + (size_t)RP * KP * 2;
    const size_t OFF_H = OFF_V + (size_t)OD * RP * 4;
    const size_t NEED  = OFF_H + (size_t)B_ * RP * 2;         // ~30.7 MB

    if (ws_size < NEED) {
        hipMemsetAsync(out, 0, (size_t)out_size * sizeof(float), stream);
        dim3 grid(B_ / BM, RP / BN);
        fused_tilednn<<<grid, 256, 0, stream>>>(x, tile1, alphas1, tile2, alphas2, out);
        return;
    }

    unsigned short* Xsw = (unsigned short*)((char*)d_ws + OFF_X);
    unsigned short* Ssw = (unsigned short*)((char*)d_ws + OFF_S);
    float*          V   = (float*)((char*)d_ws + OFF_V);
    unsigned short* Hr  = (unsigned short*)((char*)d_ws + OFF_H);

    prep<<<NB_X + NB_S + NB_V, 256, 0, stream>>>(x, tile1, tile2, alphas1, alphas2,
                                                 Xsw, Ssw, V);
    gemm1<<<512, 256, 0, stream>>>(Xsw, Ssw, Hr);
    gemm2<<<B_ / 4, 256, 0, stream>>>(Hr, V, out);
}